// Round 1
// baseline (441.778 us; speedup 1.0000x reference)
//
#include <hip/hip_runtime.h>
#include <math.h>

#define TPB 1024
#define EPT 64          // 65536 / 1024 elements per thread
#define NCOLS 65536
#define MROWS 256

__device__ __forceinline__ float waveReduceSum(float v) {
#pragma unroll
  for (int off = 32; off > 0; off >>= 1) v += __shfl_xor(v, off, 64);
  return v;
}
__device__ __forceinline__ float waveReduceMax(float v) {
#pragma unroll
  for (int off = 32; off > 0; off >>= 1) v = fmaxf(v, __shfl_xor(v, off, 64));
  return v;
}
__device__ __forceinline__ float waveReduceMin(float v) {
#pragma unroll
  for (int off = 32; off > 0; off >>= 1) v = fminf(v, __shfl_xor(v, off, 64));
  return v;
}

// Evaluate f = sum(sigmoid(z+lam)) - K and S = sum(p*(1-p)) over the whole row.
// Block-uniform result: every thread ends with identical (f,S).
__device__ __forceinline__ void evalFS(const float (&z)[EPT], float lam, float K,
                                       float* red, int wid, int lane,
                                       float& f_out, float& S_out) {
  float sp = 0.0f, ss = 0.0f;
#pragma unroll
  for (int i = 0; i < EPT; ++i) {
    float t = z[i] + lam;
    float p = 1.0f / (1.0f + __expf(-t));
    sp += p;
    ss += p * (1.0f - p);
  }
  sp = waveReduceSum(sp);
  ss = waveReduceSum(ss);
  __syncthreads();                 // protect red[] from previous use (WAR)
  if (lane == 0) { red[wid] = sp; red[16 + wid] = ss; }
  __syncthreads();
  float tsp = 0.0f, tss = 0.0f;
#pragma unroll
  for (int j = 0; j < 16; ++j) { tsp += red[j]; tss += red[16 + j]; }
  f_out = tsp - K;
  S_out = tss;
}

__device__ __forceinline__ float logit_clipped(float x) {
  x = fminf(fmaxf(x, 1e-6f), 1.0f - 1e-6f);
  return __logf(x) - log1pf(-x);
}

__global__ __launch_bounds__(TPB, 4) void row_solve_kernel(
    const float* __restrict__ logits, const float* __restrict__ pos,
    float* __restrict__ rowout) {
  const int row = blockIdx.x;
  const int tid = threadIdx.x;
  const int wid = tid >> 6;
  const int lane = tid & 63;
  const float* zrow = logits + (size_t)row * NCOLS;
  const float* prow = pos + (size_t)row * NCOLS;

  __shared__ float red[64];

  // ---- pass 1: load z into registers; accumulate sum(pos), sum(sigmoid(z)), max/min z
  float z[EPT];
  float s_sig = 0.0f, s_pos = 0.0f;
  float zmax = -3.0e38f, zmin = 3.0e38f;
#pragma unroll
  for (int i = 0; i < EPT; ++i) {
    float zv = zrow[i * TPB + tid];
    float pv = prow[i * TPB + tid];
    z[i] = zv;
    s_pos += pv;
    s_sig += 1.0f / (1.0f + __expf(-zv));
    zmax = fmaxf(zmax, zv);
    zmin = fminf(zmin, zv);
  }
  s_sig = waveReduceSum(s_sig);
  s_pos = waveReduceSum(s_pos);
  zmax = waveReduceMax(zmax);
  zmin = waveReduceMin(zmin);
  if (lane == 0) {
    red[wid] = s_sig; red[16 + wid] = s_pos;
    red[32 + wid] = zmax; red[48 + wid] = zmin;
  }
  __syncthreads();
  float t_sig = 0.0f, t_pos = 0.0f, t_max = -3.0e38f, t_min = 3.0e38f;
#pragma unroll
  for (int j = 0; j < 16; ++j) {
    t_sig += red[j];
    t_pos += red[16 + j];
    t_max = fmaxf(t_max, red[32 + j]);
    t_min = fminf(t_min, red[48 + j]);
  }

  const float n = (float)NCOLS;
  const float K_high = t_pos;
  float K = K_high * 0.25f;                 // / BLOCK_AREA
  K = fminf(fmaxf(K, 0.0f), n);             // clip (done twice in ref; idempotent)
  const float L0 = -20.0f - t_max;
  const float U0 = 20.0f - t_min;
  float L = L0, U = U0;

  const float p0_mean = t_sig / n;
  const float t_mean = K / n;
  float lam = logit_clipped(t_mean) - logit_clipped(p0_mean);
  lam = fminf(fmaxf(lam, L), U);

  float f, S;
  evalFS(z, lam, K, red, wid, lane, f, S);

  // ---- safeguarded Newton / bisection, exactly MAX_ITERS=20 iterations.
  // All branch conditions are block-uniform (computed from identical reduced
  // scalars on every thread), so the __syncthreads inside evalFS is safe.
  for (int it = 0; it < 20; ++it) {
    const bool done = fabsf(f) <= 1e-7f;
    const float newton = lam - f / (S + 1e-18f);
    const bool oob = (newton < L) || (newton > U);
    float lam_try, f_try, S_try;
    if (oob || done) {
      lam_try = lam; f_try = f; S_try = S;   // ref re-evaluates at same lam: bit-identical
    } else {
      lam_try = newton;
      evalFS(z, lam_try, K, red, wid, lane, f_try, S_try);
    }
    const bool no_improve = (fabsf(f_try) > fabsf(f)) && !oob && !done;
    const float mid = 0.5f * (L + U);
    float lam_next, f_next, S_next;
    if (oob || no_improve) {
      lam_next = mid;
      evalFS(z, lam_next, K, red, wid, lane, f_next, S_next);
    } else {
      lam_next = lam_try; f_next = f_try; S_next = S_try;
    }
    if (f_next > 0.0f) U = lam_next; else L = lam_next;
    lam = lam_next; f = f_next; S = S_next;
  }
  lam = fminf(fmaxf(lam, L), U);

  // ---- epilogue: block-weighted BCE + dice partials
  float loss = 0.0f, inter = 0.0f, psum = 0.0f;
#pragma unroll
  for (int i = 0; i < EPT; ++i) {
    float pv = prow[i * TPB + tid];          // re-read pos (L3-resident)
    float zs = z[i] + lam;
    float azs = fabsf(zs);
    float q = __expf(-azs);
    float lg = log1pf(q);                    // log1p(exp(-|zs|))
    float mz = fmaxf(zs, 0.0f);
    loss += 4.0f * mz - zs * pv + 4.0f * lg;
    float sig = (zs >= 0.0f) ? (1.0f / (1.0f + q)) : (q / (1.0f + q));
    inter += sig * pv;
    psum += sig;
  }
  loss = waveReduceSum(loss);
  inter = waveReduceSum(inter);
  psum = waveReduceSum(psum);
  __syncthreads();
  if (lane == 0) { red[wid] = loss; red[16 + wid] = inter; red[32 + wid] = psum; }
  __syncthreads();
  if (tid == 0) {
    float tl = 0.0f, ti = 0.0f, tp = 0.0f;
#pragma unroll
    for (int j = 0; j < 16; ++j) { tl += red[j]; ti += red[16 + j]; tp += red[32 + j]; }
    float* o = rowout + row * 4;
    o[0] = tl; o[1] = ti; o[2] = tp; o[3] = K_high;
  }
}

__global__ void final_kernel(const float* __restrict__ rowout, float* __restrict__ out) {
  const int t = threadIdx.x;                 // 256 threads, 4 waves
  const float loss = rowout[t * 4 + 0];
  const float inter = rowout[t * 4 + 1];
  const float psum = rowout[t * 4 + 2];
  const float K_high = rowout[t * 4 + 3];
  float maskc = loss / (512.0f * 512.0f);
  float dicec = 1.0f - (2.0f * inter + 1.0f) / (4.0f * psum + K_high + 1.0f);
  maskc = waveReduceSum(maskc);
  dicec = waveReduceSum(dicec);
  __shared__ float red[8];
  const int wid = t >> 6, lane = t & 63;
  if (lane == 0) { red[wid] = maskc; red[4 + wid] = dicec; }
  __syncthreads();
  if (t == 0) {
    float a = 0.0f, b = 0.0f;
    for (int j = 0; j < 4; ++j) { a += red[j]; b += red[4 + j]; }
    out[0] = a / 256.0f;
    out[1] = b / 256.0f;
  }
}

extern "C" void kernel_launch(void* const* d_in, const int* in_sizes, int n_in,
                              void* d_out, int out_size, void* d_ws, size_t ws_size,
                              hipStream_t stream) {
  const float* logits = (const float*)d_in[0];
  const float* pos = (const float*)d_in[1];
  float* rowout = (float*)d_ws;              // 256 * 4 floats
  row_solve_kernel<<<MROWS, TPB, 0, stream>>>(logits, pos, rowout);
  final_kernel<<<1, 256, 0, stream>>>(rowout, (float*)d_out);
}

// Round 2
// 89.724 us; speedup vs baseline: 4.9238x; 4.9238x over previous
//
#include <hip/hip_runtime.h>
#include <math.h>

#define TPB 1024
#define NCOLS 65536
#define MROWS 256
#define NBINS 2048
#define NV4 (NCOLS / 4 / TPB)   // 16 float4 iterations per thread
#define ZLO 20.0f               // histogram covers [-20, 20]
#define ZSCALE 1024.0f          // fixed-point scale for bin z-sums

__device__ __forceinline__ float waveReduceSum(float v) {
#pragma unroll
  for (int off = 32; off > 0; off >>= 1) v += __shfl_xor(v, off, 64);
  return v;
}

// Block-uniform sum of two values (every thread gets identical results).
__device__ __forceinline__ void blockReduce2(float a, float b, float* red,
                                             int wid, int lane, float& A, float& B) {
  a = waveReduceSum(a);
  b = waveReduceSum(b);
  __syncthreads();                       // WAR protection on red[]
  if (lane == 0) { red[wid] = a; red[16 + wid] = b; }
  __syncthreads();
  float ta = 0.0f, tb = 0.0f;
#pragma unroll
  for (int j = 0; j < 16; ++j) { ta += red[j]; tb += red[16 + j]; }
  A = ta; B = tb;
}

__device__ __forceinline__ void blockReduce3(float a, float b, float c, float* red,
                                             int wid, int lane,
                                             float& A, float& B, float& C) {
  a = waveReduceSum(a);
  b = waveReduceSum(b);
  c = waveReduceSum(c);
  __syncthreads();
  if (lane == 0) { red[wid] = a; red[16 + wid] = b; red[32 + wid] = c; }
  __syncthreads();
  float ta = 0.0f, tb = 0.0f, tc = 0.0f;
#pragma unroll
  for (int j = 0; j < 16; ++j) { ta += red[j]; tb += red[16 + j]; tc += red[32 + j]; }
  A = ta; B = tb; C = tc;
}

__global__ __launch_bounds__(TPB) void row_kernel(
    const float* __restrict__ logits, const float* __restrict__ pos,
    float* __restrict__ rowout) {
  __shared__ unsigned int h_cnt[NBINS];
  __shared__ int h_sum[NBINS];
  __shared__ float red[64];

  const int row = blockIdx.x;
  const int tid = threadIdx.x;
  const int wid = tid >> 6;
  const int lane = tid & 63;
  const float4* z4 = (const float4*)(logits + (size_t)row * NCOLS);
  const float4* p4 = (const float4*)(pos + (size_t)row * NCOLS);

  // ---- zero histogram
  for (int b = tid; b < NBINS; b += TPB) { h_cnt[b] = 0u; h_sum[b] = 0; }
  __syncthreads();

  // ---- phase 1: histogram z, sum pos
  const float INVW = (float)NBINS / (2.0f * ZLO);   // 51.2 bins per unit
  float s_pos = 0.0f;
#pragma unroll
  for (int i = 0; i < NV4; ++i) {
    float4 zv = z4[i * TPB + tid];
    float4 pv = p4[i * TPB + tid];
    s_pos += (pv.x + pv.y) + (pv.z + pv.w);
    float zz[4] = {zv.x, zv.y, zv.z, zv.w};
#pragma unroll
    for (int c = 0; c < 4; ++c) {
      float z = zz[c];
      int b = (int)((z + ZLO) * INVW);
      b = min(max(b, 0), NBINS - 1);
      atomicAdd(&h_cnt[b], 1u);
      atomicAdd(&h_sum[b], __float2int_rn(z * ZSCALE));
    }
  }

  float K_high, dummy;
  blockReduce2(s_pos, 0.0f, red, wid, lane, K_high, dummy);
  float K = fminf(fmaxf(K_high * 0.25f, 0.0f), (float)NCOLS);

  // histogram complete & visible after the syncthreads inside blockReduce2
  const float c0 = (float)h_cnt[tid];
  const float c1 = (float)h_cnt[tid + TPB];
  const float zb0 = (c0 > 0.0f) ? (float)h_sum[tid] / (ZSCALE * c0) : 0.0f;
  const float zb1 = (c1 > 0.0f) ? (float)h_sum[tid + TPB] / (ZSCALE * c1) : 0.0f;

  // ---- phase 2: safeguarded Newton on the histogram (block-uniform control)
  float Lb = -2.0f * ZLO, Ub = 2.0f * ZLO, lam = 0.0f;
  for (int it = 0; it < 40; ++it) {
    float p0 = 1.0f / (1.0f + __expf(-(zb0 + lam)));
    float p1 = 1.0f / (1.0f + __expf(-(zb1 + lam)));
    float fp = c0 * p0 + c1 * p1;
    float sp = c0 * p0 * (1.0f - p0) + c1 * p1 * (1.0f - p1);
    float F, S;
    blockReduce2(fp, sp, red, wid, lane, F, S);
    float f = F - K;
    if (fabsf(f) <= 1e-3f) break;          // block-uniform break
    if (f > 0.0f) Ub = lam; else Lb = lam;
    float newton = lam - f / (S + 1e-12f);
    lam = (newton > Lb && newton < Ub) ? newton : 0.5f * (Lb + Ub);
  }

  // ---- phase 3: exact BCE + dice partials (z, pos re-read; L3-resident)
  float loss = 0.0f, inter = 0.0f, psum = 0.0f;
#pragma unroll
  for (int i = 0; i < NV4; ++i) {
    float4 zv = z4[i * TPB + tid];
    float4 pv = p4[i * TPB + tid];
    float zz[4] = {zv.x, zv.y, zv.z, zv.w};
    float pp[4] = {pv.x, pv.y, pv.z, pv.w};
#pragma unroll
    for (int c = 0; c < 4; ++c) {
      float zs = zz[c] + lam;
      float pvv = pp[c];
      float azs = fabsf(zs);
      float q = __expf(-azs);
      float lg = __logf(1.0f + q);
      float mz = fmaxf(zs, 0.0f);
      loss += 4.0f * mz - zs * pvv + 4.0f * lg;
      float sig = (zs >= 0.0f) ? (1.0f / (1.0f + q)) : (q / (1.0f + q));
      inter += sig * pvv;
      psum += sig;
    }
  }
  float TL, TI, TP;
  blockReduce3(loss, inter, psum, red, wid, lane, TL, TI, TP);
  if (tid == 0) {
    float* o = rowout + row * 4;
    o[0] = TL; o[1] = TI; o[2] = TP; o[3] = K_high;
  }
}

__global__ void final_kernel(const float* __restrict__ rowout, float* __restrict__ out) {
  const int t = threadIdx.x;               // 256 threads, 4 waves
  const float loss = rowout[t * 4 + 0];
  const float inter = rowout[t * 4 + 1];
  const float psum = rowout[t * 4 + 2];
  const float K_high = rowout[t * 4 + 3];
  float maskc = loss / (512.0f * 512.0f);
  float dicec = 1.0f - (2.0f * inter + 1.0f) / (4.0f * psum + K_high + 1.0f);
  maskc = waveReduceSum(maskc);
  dicec = waveReduceSum(dicec);
  __shared__ float red[8];
  const int wid = t >> 6, lane = t & 63;
  if (lane == 0) { red[wid] = maskc; red[4 + wid] = dicec; }
  __syncthreads();
  if (t == 0) {
    float a = 0.0f, b = 0.0f;
    for (int j = 0; j < 4; ++j) { a += red[j]; b += red[4 + j]; }
    out[0] = a / 256.0f;
    out[1] = b / 256.0f;
  }
}

extern "C" void kernel_launch(void* const* d_in, const int* in_sizes, int n_in,
                              void* d_out, int out_size, void* d_ws, size_t ws_size,
                              hipStream_t stream) {
  const float* logits = (const float*)d_in[0];
  const float* pos = (const float*)d_in[1];
  float* rowout = (float*)d_ws;            // 256 * 4 floats
  row_kernel<<<MROWS, TPB, 0, stream>>>(logits, pos, rowout);
  final_kernel<<<1, 256, 0, stream>>>(rowout, (float*)d_out);
}

// Round 3
// 38.439 us; speedup vs baseline: 11.4931x; 2.3342x over previous
//
#include <hip/hip_runtime.h>
#include <math.h>

#define NCOLS 65536
#define MROWS 256
#define NBINS 1024
#define CHUNKS 8
#define CELEMS (NCOLS / CHUNKS)          // 8192 elements per chunk
#define K1_TPB 256
#define K1_ITERS (CELEMS / 4 / K1_TPB)   // 8 float4 iterations per thread
#define ZLO 20.0f
#define INVW ((float)NBINS / (2.0f * ZLO))   // 25.6 bins per unit
#define PSCALE 8192.0f                   // fixed-point scale for per-bin pos sums

__device__ __forceinline__ float waveReduceSum(float v) {
#pragma unroll
  for (int off = 32; off > 0; off >>= 1) v += __shfl_xor(v, off, 64);
  return v;
}

// ---------------- K1: stream data once; per-chunk histograms ----------------
__global__ __launch_bounds__(K1_TPB) void hist_kernel(
    const float* __restrict__ logits, const float* __restrict__ pos,
    unsigned int* __restrict__ gcnt, int* __restrict__ gpbin,
    float* __restrict__ gpos, float* __restrict__ gzp) {
  __shared__ unsigned int cnt[NBINS];
  __shared__ int pbin[NBINS];
  __shared__ float red[8];
  const int blk = blockIdx.x;
  const int row = blk / CHUNKS, chunk = blk % CHUNKS;
  const int tid = threadIdx.x, wid = tid >> 6, lane = tid & 63;

  for (int b = tid; b < NBINS; b += K1_TPB) { cnt[b] = 0u; pbin[b] = 0; }
  __syncthreads();

  const float4* z4 = (const float4*)(logits + (size_t)row * NCOLS + (size_t)chunk * CELEMS);
  const float4* p4 = (const float4*)(pos + (size_t)row * NCOLS + (size_t)chunk * CELEMS);
  float s_pos = 0.0f, s_zp = 0.0f;
#pragma unroll
  for (int i = 0; i < K1_ITERS; ++i) {
    float4 zv = z4[i * K1_TPB + tid];
    float4 pv = p4[i * K1_TPB + tid];
    s_pos += (pv.x + pv.y) + (pv.z + pv.w);
    s_zp += zv.x * pv.x + zv.y * pv.y + zv.z * pv.z + zv.w * pv.w;
    float zz[4] = {zv.x, zv.y, zv.z, zv.w};
    float pp[4] = {pv.x, pv.y, pv.z, pv.w};
#pragma unroll
    for (int c = 0; c < 4; ++c) {
      int b = (int)((zz[c] + ZLO) * INVW);
      b = min(max(b, 0), NBINS - 1);
      atomicAdd(&cnt[b], 1u);                                // integer: deterministic
      atomicAdd(&pbin[b], __float2int_rn(pp[c] * PSCALE));   // fixed-point: deterministic
    }
  }
  __syncthreads();
  for (int b = tid; b < NBINS; b += K1_TPB) {
    gcnt[(size_t)blk * NBINS + b] = cnt[b];
    gpbin[(size_t)blk * NBINS + b] = pbin[b];
  }
  s_pos = waveReduceSum(s_pos);
  s_zp = waveReduceSum(s_zp);
  if (lane == 0) { red[wid] = s_pos; red[4 + wid] = s_zp; }
  __syncthreads();
  if (tid == 0) {
    gpos[blk] = (red[0] + red[1]) + (red[2] + red[3]);
    gzp[blk] = (red[4] + red[5]) + (red[6] + red[7]);
  }
}

// ------------- K2: per-row Newton on histogram + binned loss eval -----------
#define K2_TPB 256
#define BPT (NBINS / K2_TPB)   // 4 bins per thread

__global__ __launch_bounds__(K2_TPB) void solve_kernel(
    const unsigned int* __restrict__ gcnt, const int* __restrict__ gpbin,
    const float* __restrict__ gpos, const float* __restrict__ gzp,
    float* __restrict__ rowout) {
  __shared__ float red[12];
  const int row = blockIdx.x;
  const int tid = threadIdx.x, wid = tid >> 6, lane = tid & 63;

  float cntf[BPT], pbf[BPT], zc[BPT];
#pragma unroll
  for (int j = 0; j < BPT; ++j) {
    const int b = tid + j * K2_TPB;
    unsigned int c = 0u; int pq = 0;
    for (int ch = 0; ch < CHUNKS; ++ch) {
      const size_t base = (size_t)(row * CHUNKS + ch) * NBINS + b;
      c += gcnt[base];
      pq += gpbin[base];
    }
    cntf[j] = (float)c;
    pbf[j] = (float)pq * (1.0f / PSCALE);
    zc[j] = -ZLO + ((float)b + 0.5f) / INVW;   // bin center
  }
  float Kh = 0.0f, Szp = 0.0f;
  for (int ch = 0; ch < CHUNKS; ++ch) {        // fixed order: deterministic
    Kh += gpos[row * CHUNKS + ch];
    Szp += gzp[row * CHUNKS + ch];
  }
  const float K = fminf(fmaxf(Kh * 0.25f, 0.0f), (float)NCOLS);

  // safeguarded Newton/bisection; all control block-uniform
  float Lb = -2.0f * ZLO, Ub = 2.0f * ZLO, lam = 0.0f;
  for (int it = 0; it < 30; ++it) {
    float fp = 0.0f, sp = 0.0f;
#pragma unroll
    for (int j = 0; j < BPT; ++j) {
      float p = 1.0f / (1.0f + __expf(-(zc[j] + lam)));
      fp += cntf[j] * p;
      sp += cntf[j] * p * (1.0f - p);
    }
    fp = waveReduceSum(fp);
    sp = waveReduceSum(sp);
    __syncthreads();
    if (lane == 0) { red[wid] = fp; red[4 + wid] = sp; }
    __syncthreads();
    const float F = (red[0] + red[1]) + (red[2] + red[3]);
    const float S = (red[4] + red[5]) + (red[6] + red[7]);
    const float f = F - K;
    if (fabsf(f) <= 1e-2f) break;            // lambda err ~ 1e-6
    if (f > 0.0f) Ub = lam; else Lb = lam;
    const float newton = lam - f / (S + 1e-12f);
    lam = (newton > Lb && newton < Ub) ? newton : 0.5f * (Lb + Ub);
  }

  // binned loss: 4*sum cnt*(max(zs,0)+log1p(exp(-|zs|))) - (sum z*pos + lam*K_high)
  float tl = 0.0f, ti = 0.0f, tp = 0.0f;
#pragma unroll
  for (int j = 0; j < BPT; ++j) {
    const float zs = zc[j] + lam;
    const float e = __expf(-fabsf(zs));
    const float lg = __logf(1.0f + e);
    const float mz = fmaxf(zs, 0.0f);
    const float sig = (zs >= 0.0f) ? (1.0f / (1.0f + e)) : (e / (1.0f + e));
    tl += cntf[j] * (mz + lg);
    ti += pbf[j] * sig;
    tp += cntf[j] * sig;
  }
  tl = waveReduceSum(tl);
  ti = waveReduceSum(ti);
  tp = waveReduceSum(tp);
  __syncthreads();
  if (lane == 0) { red[wid] = tl; red[4 + wid] = ti; red[8 + wid] = tp; }
  __syncthreads();
  if (tid == 0) {
    const float loss = 4.0f * ((red[0] + red[1]) + (red[2] + red[3])) - (Szp + lam * Kh);
    float* o = rowout + row * 4;
    o[0] = loss;
    o[1] = (red[4] + red[5]) + (red[6] + red[7]);
    o[2] = (red[8] + red[9]) + (red[10] + red[11]);
    o[3] = Kh;
  }
}

// ---------------- K3: combine 256 rows into the two scalars -----------------
__global__ void final_kernel(const float* __restrict__ rowout, float* __restrict__ out) {
  const int t = threadIdx.x;                 // 256 threads, 4 waves
  const float loss = rowout[t * 4 + 0];
  const float inter = rowout[t * 4 + 1];
  const float psum = rowout[t * 4 + 2];
  const float Kh = rowout[t * 4 + 3];
  float maskc = loss * (1.0f / (512.0f * 512.0f));
  float dicec = 1.0f - (2.0f * inter + 1.0f) / (4.0f * psum + Kh + 1.0f);
  maskc = waveReduceSum(maskc);
  dicec = waveReduceSum(dicec);
  __shared__ float red[8];
  const int wid = t >> 6, lane = t & 63;
  if (lane == 0) { red[wid] = maskc; red[4 + wid] = dicec; }
  __syncthreads();
  if (t == 0) {
    float a = 0.0f, b = 0.0f;
    for (int j = 0; j < 4; ++j) { a += red[j]; b += red[4 + j]; }
    out[0] = a / 256.0f;
    out[1] = b / 256.0f;
  }
}

// -------- fallback (round-2 style, 4 KB ws) in case ws is too small ---------
#define FB_TPB 1024
#define FB_NV4 (NCOLS / 4 / FB_TPB)
__device__ __forceinline__ void fbReduce2(float a, float b, float* red,
                                          int wid, int lane, float& A, float& B) {
  a = waveReduceSum(a);
  b = waveReduceSum(b);
  __syncthreads();
  if (lane == 0) { red[wid] = a; red[16 + wid] = b; }
  __syncthreads();
  float ta = 0.0f, tb = 0.0f;
#pragma unroll
  for (int j = 0; j < 16; ++j) { ta += red[j]; tb += red[16 + j]; }
  A = ta; B = tb;
}

__global__ __launch_bounds__(FB_TPB) void fb_row_kernel(
    const float* __restrict__ logits, const float* __restrict__ pos,
    float* __restrict__ rowout) {
  __shared__ unsigned int h_cnt[2048];
  __shared__ int h_sum[2048];
  __shared__ float red[64];
  const int row = blockIdx.x;
  const int tid = threadIdx.x, wid = tid >> 6, lane = tid & 63;
  const float4* z4 = (const float4*)(logits + (size_t)row * NCOLS);
  const float4* p4 = (const float4*)(pos + (size_t)row * NCOLS);
  for (int b = tid; b < 2048; b += FB_TPB) { h_cnt[b] = 0u; h_sum[b] = 0; }
  __syncthreads();
  const float invw = 2048.0f / 40.0f;
  float s_pos = 0.0f;
#pragma unroll
  for (int i = 0; i < FB_NV4; ++i) {
    float4 zv = z4[i * FB_TPB + tid];
    float4 pv = p4[i * FB_TPB + tid];
    s_pos += (pv.x + pv.y) + (pv.z + pv.w);
    float zz[4] = {zv.x, zv.y, zv.z, zv.w};
#pragma unroll
    for (int c = 0; c < 4; ++c) {
      int b = (int)((zz[c] + 20.0f) * invw);
      b = min(max(b, 0), 2047);
      atomicAdd(&h_cnt[b], 1u);
      atomicAdd(&h_sum[b], __float2int_rn(zz[c] * 1024.0f));
    }
  }
  float K_high, dummy;
  fbReduce2(s_pos, 0.0f, red, wid, lane, K_high, dummy);
  float K = fminf(fmaxf(K_high * 0.25f, 0.0f), (float)NCOLS);
  const float c0 = (float)h_cnt[tid];
  const float c1 = (float)h_cnt[tid + FB_TPB];
  const float zb0 = (c0 > 0.0f) ? (float)h_sum[tid] / (1024.0f * c0) : 0.0f;
  const float zb1 = (c1 > 0.0f) ? (float)h_sum[tid + FB_TPB] / (1024.0f * c1) : 0.0f;
  float Lb = -40.0f, Ub = 40.0f, lam = 0.0f;
  for (int it = 0; it < 40; ++it) {
    float p0 = 1.0f / (1.0f + __expf(-(zb0 + lam)));
    float p1 = 1.0f / (1.0f + __expf(-(zb1 + lam)));
    float F, S;
    fbReduce2(c0 * p0 + c1 * p1, c0 * p0 * (1.0f - p0) + c1 * p1 * (1.0f - p1),
              red, wid, lane, F, S);
    float f = F - K;
    if (fabsf(f) <= 1e-3f) break;
    if (f > 0.0f) Ub = lam; else Lb = lam;
    float newton = lam - f / (S + 1e-12f);
    lam = (newton > Lb && newton < Ub) ? newton : 0.5f * (Lb + Ub);
  }
  float loss = 0.0f, inter = 0.0f, psum = 0.0f;
#pragma unroll
  for (int i = 0; i < FB_NV4; ++i) {
    float4 zv = z4[i * FB_TPB + tid];
    float4 pv = p4[i * FB_TPB + tid];
    float zz[4] = {zv.x, zv.y, zv.z, zv.w};
    float pp[4] = {pv.x, pv.y, pv.z, pv.w};
#pragma unroll
    for (int c = 0; c < 4; ++c) {
      float zs = zz[c] + lam;
      float q = __expf(-fabsf(zs));
      loss += 4.0f * fmaxf(zs, 0.0f) - zs * pp[c] + 4.0f * __logf(1.0f + q);
      float sig = (zs >= 0.0f) ? (1.0f / (1.0f + q)) : (q / (1.0f + q));
      inter += sig * pp[c];
      psum += sig;
    }
  }
  float TL, TI;
  fbReduce2(loss, inter, red, wid, lane, TL, TI);
  float TP, d2;
  fbReduce2(psum, 0.0f, red, wid, lane, TP, d2);
  if (tid == 0) {
    float* o = rowout + row * 4;
    o[0] = TL; o[1] = TI; o[2] = TP; o[3] = K_high;
  }
}

extern "C" void kernel_launch(void* const* d_in, const int* in_sizes, int n_in,
                              void* d_out, int out_size, void* d_ws, size_t ws_size,
                              hipStream_t stream) {
  const float* logits = (const float*)d_in[0];
  const float* pos = (const float*)d_in[1];
  char* ws = (char*)d_ws;

  const size_t nblk = (size_t)MROWS * CHUNKS;
  const size_t off_gcnt = 0;
  const size_t off_gpbin = off_gcnt + nblk * NBINS * sizeof(unsigned int);
  const size_t off_gpos = off_gpbin + nblk * NBINS * sizeof(int);
  const size_t off_gzp = off_gpos + nblk * sizeof(float);
  const size_t off_rowout = off_gzp + nblk * sizeof(float);
  const size_t needed = off_rowout + (size_t)MROWS * 4 * sizeof(float);

  if (ws_size >= needed) {
    unsigned int* gcnt = (unsigned int*)(ws + off_gcnt);
    int* gpbin = (int*)(ws + off_gpbin);
    float* gpos = (float*)(ws + off_gpos);
    float* gzp = (float*)(ws + off_gzp);
    float* rowout = (float*)(ws + off_rowout);
    hist_kernel<<<(int)nblk, K1_TPB, 0, stream>>>(logits, pos, gcnt, gpbin, gpos, gzp);
    solve_kernel<<<MROWS, K2_TPB, 0, stream>>>(gcnt, gpbin, gpos, gzp, rowout);
    final_kernel<<<1, 256, 0, stream>>>(rowout, (float*)d_out);
  } else {
    float* rowout = (float*)d_ws;          // 4 KB fallback path
    fb_row_kernel<<<MROWS, FB_TPB, 0, stream>>>(logits, pos, rowout);
    final_kernel<<<1, 256, 0, stream>>>(rowout, (float*)d_out);
  }
}